// Round 1
// baseline (3277.530 us; speedup 1.0000x reference)
//
#include <hip/hip_runtime.h>
#include <hip/hip_bf16.h>

#define DIMN 1024
#define NHEAD 8
#define ESPL 128
#define NB 4
#define SEQ 2048
#define NROWS (NB * SEQ)
#define LNEPS 1e-6f

typedef unsigned short u16;
typedef unsigned int u32;

__device__ __forceinline__ u16 f2bf(float f) {
  u32 u = __float_as_uint(f);
  u += 0x7FFFu + ((u >> 16) & 1u);  // round-to-nearest-even
  return (u16)(u >> 16);
}

__device__ __forceinline__ float eluf(float x) { return x > 0.f ? x : expm1f(x); }

// 256-thread block sum (4 waves). rb is shared float[8].
__device__ __forceinline__ float block_sum256(float v, float* rb, int t) {
#pragma unroll
  for (int o = 32; o > 0; o >>= 1) v += __shfl_down(v, o);
  __syncthreads();  // protect rb from previous use
  if ((t & 63) == 0) rb[t >> 6] = v;
  __syncthreads();
  return rb[0] + rb[1] + rb[2] + rb[3];
}

// ---------------- GEMM1: mod = x @ W_in  (8192x1024 @ 1024x1024) ----------------
#define BM 128
#define BN 128
#define BK 8

__global__ __launch_bounds__(256) void gemm_xwin(const float* __restrict__ A,
                                                 const float* __restrict__ B,
                                                 float* __restrict__ C) {
  __shared__ float As[BK][BM + 4];
  __shared__ float Bs[BK][BN + 4];
  const int t = threadIdx.x;
  const int m0 = blockIdx.y * BM;
  const int n0 = blockIdx.x * BN;
  const int lm = t >> 1;
  const int lk = (t & 1) << 2;
  const int bk = t >> 5;
  const int bn = (t & 31) << 2;
  const int tx = t & 15;
  const int ty = t >> 4;
  const float* Ap = A + (size_t)(m0 + lm) * DIMN + lk;
  const float* Bp = B + (size_t)bk * DIMN + n0 + bn;
  float acc[8][8] = {};
  for (int kt = 0; kt < DIMN; kt += BK) {
    float4 av = *(const float4*)(Ap + kt);
    float4 bv = *(const float4*)(Bp + (size_t)kt * DIMN);
    As[lk + 0][lm] = av.x;
    As[lk + 1][lm] = av.y;
    As[lk + 2][lm] = av.z;
    As[lk + 3][lm] = av.w;
    *(float4*)&Bs[bk][bn] = bv;
    __syncthreads();
#pragma unroll
    for (int k2 = 0; k2 < BK; k2++) {
      float a[8], b[8];
      *(float4*)(a + 0) = *(const float4*)&As[k2][ty * 8 + 0];
      *(float4*)(a + 4) = *(const float4*)&As[k2][ty * 8 + 4];
      *(float4*)(b + 0) = *(const float4*)&Bs[k2][tx * 8 + 0];
      *(float4*)(b + 4) = *(const float4*)&Bs[k2][tx * 8 + 4];
#pragma unroll
      for (int i = 0; i < 8; i++)
#pragma unroll
        for (int j = 0; j < 8; j++) acc[i][j] += a[i] * b[j];
    }
    __syncthreads();
  }
  for (int i = 0; i < 8; i++) {
    float* Cp = C + (size_t)(m0 + ty * 8 + i) * DIMN + n0 + tx * 8;
    *(float4*)(Cp + 0) = make_float4(acc[i][0], acc[i][1], acc[i][2], acc[i][3]);
    *(float4*)(Cp + 4) = make_float4(acc[i][4], acc[i][5], acc[i][6], acc[i][7]);
  }
}

// ------- LN1 fused with per-head QKV projections; 4 rows per block -------
__global__ __launch_bounds__(256) void ln_qkv(const float* __restrict__ modp,
                                              const float* __restrict__ gamma,
                                              const float* __restrict__ beta,
                                              const float* __restrict__ Wq,
                                              const float* __restrict__ Wk,
                                              const float* __restrict__ Wv,
                                              u16* __restrict__ qo, u16* __restrict__ ko,
                                              u16* __restrict__ vo) {
  __shared__ float hs[4][DIMN];
  __shared__ float rb[8];
  const int t = threadIdx.x;
  const int row0 = blockIdx.x << 2;
  for (int r = 0; r < 4; r++) {
    const float* xr = modp + (size_t)(row0 + r) * DIMN;
    float4 xv = ((const float4*)xr)[t];
    float s = xv.x + xv.y + xv.z + xv.w;
    s = block_sum256(s, rb, t);
    float mean = s * (1.f / DIMN);
    float dx = xv.x - mean, dy = xv.y - mean, dz = xv.z - mean, dw = xv.w - mean;
    float sq = block_sum256(dx * dx + dy * dy + dz * dz + dw * dw, rb, t);
    float rstd = rsqrtf(sq * (1.f / DIMN) + LNEPS);
    float4 gv = ((const float4*)gamma)[t];
    float4 bv = ((const float4*)beta)[t];
    float* hr = hs[r] + (t << 2);
    hr[0] = dx * rstd * gv.x + bv.x;
    hr[1] = dy * rstd * gv.y + bv.y;
    hr[2] = dz * rstd * gv.z + bv.z;
    hr[3] = dw * rstd * gv.w + bv.w;
  }
  __syncthreads();
  const float* Ws[3] = {Wq, Wk, Wv};
  for (int mI = 0; mI < 3; mI++) {
    const float* W = Ws[mI];
    u16* o = (mI == 0) ? qo : (mI == 1) ? ko : vo;
    for (int p = 0; p < 4; p++) {
      const int oi = t + (p << 8);
      const int hh = oi >> 7;
      const int e = oi & 127;
      const float* w = W + ((size_t)hh << 14) + e;
      const float* h0 = hs[0] + (hh << 7);
      const float* h1 = hs[1] + (hh << 7);
      const float* h2 = hs[2] + (hh << 7);
      const float* h3 = hs[3] + (hh << 7);
      float a0 = 0.f, a1 = 0.f, a2 = 0.f, a3 = 0.f;
#pragma unroll 16
      for (int d = 0; d < 128; d++) {
        float wvv = w[(size_t)d << 7];
        a0 += h0[d] * wvv;
        a1 += h1[d] * wvv;
        a2 += h2[d] * wvv;
        a3 += h3[d] * wvv;
      }
      float vals[4] = {a0, a1, a2, a3};
      for (int r = 0; r < 4; r++) {
        int rowr = row0 + r;
        size_t idx = (((size_t)(rowr >> 11) * NHEAD + hh) * SEQ + (rowr & 2047)) * ESPL + e;
        o[idx] = f2bf(vals[r]);
      }
    }
  }
}

// ------- Flash attention: per (b,h) head, 32-row q-tiles, adds into mod -------
__global__ __launch_bounds__(256) void attn(const u16* __restrict__ q,
                                            const u16* __restrict__ kk,
                                            const u16* __restrict__ vv,
                                            float* __restrict__ modp) {
  __shared__ float Qs[32][132];
  __shared__ float Ks[32][132];
  __shared__ float Vs[32][132];
  __shared__ float Ss[32][33];
  __shared__ float alpha_s[32];
  __shared__ float l_s[32];
  const int t = threadIdx.x;
  const int qt = blockIdx.x;  // 0..63
  const int bh = blockIdx.y;  // 0..31
  const size_t base = (size_t)bh * SEQ * ESPL;
  {
    const u32* qp = (const u32*)(q + base + (size_t)qt * 32 * ESPL);
#pragma unroll
    for (int i = 0; i < 8; i++) {
      int p = t + (i << 8);
      int r = p >> 6, c2 = (p & 63) << 1;
      u32 u = qp[p];
      Qs[r][c2] = __uint_as_float(u << 16);
      Qs[r][c2 + 1] = __uint_as_float(u & 0xFFFF0000u);
    }
  }
  float m_r = -1e30f, l_r = 0.f;
  float acc[16];
#pragma unroll
  for (int j = 0; j < 16; j++) acc[j] = 0.f;
  const int kc = t & 31, qi = t >> 5;    // scores mapping
  const int aqr = t & 31, aec = t >> 5;  // accumulate mapping
  const int e0 = aec << 4;
  for (int kt = 0; kt < SEQ / 32; kt++) {
    __syncthreads();  // previous phase done before overwriting Ks/Vs (also covers Q load on iter 0)
    {
      const u32* kp = (const u32*)(kk + base + (size_t)kt * 32 * ESPL);
      const u32* vp = (const u32*)(vv + base + (size_t)kt * 32 * ESPL);
#pragma unroll
      for (int i = 0; i < 8; i++) {
        int p = t + (i << 8);
        int r = p >> 6, c2 = (p & 63) << 1;
        u32 u = kp[p];
        Ks[r][c2] = __uint_as_float(u << 16);
        Ks[r][c2 + 1] = __uint_as_float(u & 0xFFFF0000u);
        u32 u2 = vp[p];
        Vs[r][c2] = __uint_as_float(u2 << 16);
        Vs[r][c2 + 1] = __uint_as_float(u2 & 0xFFFF0000u);
      }
    }
    __syncthreads();
    // scores: each thread 4 rows x 1 col
#pragma unroll
    for (int pq = 0; pq < 4; pq++) {
      const int qr = qi + (pq << 3);
      const float4* Qv = (const float4*)&Qs[qr][0];
      const float4* Kv = (const float4*)&Ks[kc][0];
      float sc = 0.f;
#pragma unroll 8
      for (int d4 = 0; d4 < 32; d4++) {
        float4 a = Qv[d4];
        float4 b = Kv[d4];
        sc += a.x * b.x + a.y * b.y + a.z * b.z + a.w * b.w;
      }
      Ss[qr][kc] = sc;
    }
    __syncthreads();
    // online softmax update (one thread per q-row)
    if (t < 32) {
      float mx = m_r;
#pragma unroll
      for (int c = 0; c < 32; c++) mx = fmaxf(mx, Ss[t][c]);
      float al = expf(m_r - mx);
      float sum = 0.f;
#pragma unroll
      for (int c = 0; c < 32; c++) {
        float pv = expf(Ss[t][c] - mx);
        Ss[t][c] = pv;
        sum += pv;
      }
      l_r = l_r * al + sum;
      m_r = mx;
      alpha_s[t] = al;
      l_s[t] = l_r;
    }
    __syncthreads();
    // accumulate P @ V
    {
      const float al = alpha_s[aqr];
#pragma unroll
      for (int j = 0; j < 16; j++) acc[j] *= al;
#pragma unroll 4
      for (int c = 0; c < 32; c++) {
        const float pv = Ss[aqr][c];
        const float4* Vv = (const float4*)&Vs[c][e0];
        const float4 v0 = Vv[0], v1 = Vv[1], v2 = Vv[2], v3 = Vv[3];
        acc[0] += pv * v0.x; acc[1] += pv * v0.y; acc[2] += pv * v0.z; acc[3] += pv * v0.w;
        acc[4] += pv * v1.x; acc[5] += pv * v1.y; acc[6] += pv * v1.z; acc[7] += pv * v1.w;
        acc[8] += pv * v2.x; acc[9] += pv * v2.y; acc[10] += pv * v2.z; acc[11] += pv * v2.w;
        acc[12] += pv * v3.x; acc[13] += pv * v3.y; acc[14] += pv * v3.z; acc[15] += pv * v3.w;
      }
    }
  }
  __syncthreads();
  // stage normalized output in LDS (reuse Ks), then coalesced RMW into mod
  {
    const float linv = 1.f / l_s[aqr];
#pragma unroll
    for (int j = 0; j < 16; j++) Ks[aqr][e0 + j] = acc[j] * linv;
  }
  __syncthreads();
  const int b = bh >> 3, hh = bh & 7;
  for (int i = 0; i < 16; i++) {
    int p = t + (i << 8);
    int r = p >> 7, e = p & 127;
    size_t mi = ((size_t)(b * SEQ + qt * 32 + r)) * DIMN + (hh << 7) + e;
    modp[mi] += Ks[r][e];
  }
}

// ------- per-row mean / rstd of (mod + attention residual) -------
__global__ __launch_bounds__(256) void row_stats(const float* __restrict__ modp,
                                                 float* __restrict__ mean2,
                                                 float* __restrict__ rstd2) {
  __shared__ float rb[8];
  const int row = blockIdx.x;
  const int t = threadIdx.x;
  float4 xv = ((const float4*)(modp + (size_t)row * DIMN))[t];
  float s = block_sum256(xv.x + xv.y + xv.z + xv.w, rb, t);
  float mean = s * (1.f / DIMN);
  float dx = xv.x - mean, dy = xv.y - mean, dz = xv.z - mean, dw = xv.w - mean;
  float sq = block_sum256(dx * dx + dy * dy + dz * dz + dw * dw, rb, t);
  if (t == 0) {
    mean2[row] = mean;
    rstd2[row] = rsqrtf(sq * (1.f / DIMN) + LNEPS);
  }
}

// ------- GEMM2: out = mod + elu(LN2(mod) @ Wf + bf), LN fused in A-load -------
__global__ __launch_bounds__(256) void gemm_ffn(const float* __restrict__ modp,
                                                const float* __restrict__ Wf,
                                                const float* __restrict__ bfp,
                                                const float* __restrict__ gamma,
                                                const float* __restrict__ beta,
                                                const float* __restrict__ mean2,
                                                const float* __restrict__ rstd2,
                                                float* __restrict__ out) {
  __shared__ float As[BK][BM + 4];
  __shared__ float Bs[BK][BN + 4];
  const int t = threadIdx.x;
  const int m0 = blockIdx.y * BM;
  const int n0 = blockIdx.x * BN;
  const int lm = t >> 1;
  const int lk = (t & 1) << 2;
  const int bk = t >> 5;
  const int bn = (t & 31) << 2;
  const int tx = t & 15;
  const int ty = t >> 4;
  const int am = m0 + lm;
  const float mu = mean2[am];
  const float rs = rstd2[am];
  const float* Ap = modp + (size_t)am * DIMN + lk;
  const float* Bp = Wf + (size_t)bk * DIMN + n0 + bn;
  float acc[8][8] = {};
  for (int kt = 0; kt < DIMN; kt += BK) {
    float4 av = *(const float4*)(Ap + kt);
    float4 gv = *(const float4*)(gamma + kt + lk);
    float4 btv = *(const float4*)(beta + kt + lk);
    float4 bv = *(const float4*)(Bp + (size_t)kt * DIMN);
    As[lk + 0][lm] = (av.x - mu) * rs * gv.x + btv.x;
    As[lk + 1][lm] = (av.y - mu) * rs * gv.y + btv.y;
    As[lk + 2][lm] = (av.z - mu) * rs * gv.z + btv.z;
    As[lk + 3][lm] = (av.w - mu) * rs * gv.w + btv.w;
    *(float4*)&Bs[bk][bn] = bv;
    __syncthreads();
#pragma unroll
    for (int k2 = 0; k2 < BK; k2++) {
      float a[8], b[8];
      *(float4*)(a + 0) = *(const float4*)&As[k2][ty * 8 + 0];
      *(float4*)(a + 4) = *(const float4*)&As[k2][ty * 8 + 4];
      *(float4*)(b + 0) = *(const float4*)&Bs[k2][tx * 8 + 0];
      *(float4*)(b + 4) = *(const float4*)&Bs[k2][tx * 8 + 4];
#pragma unroll
      for (int i = 0; i < 8; i++)
#pragma unroll
        for (int j = 0; j < 8; j++) acc[i][j] += a[i] * b[j];
    }
    __syncthreads();
  }
  const float4 bf0 = *(const float4*)(bfp + n0 + tx * 8 + 0);
  const float4 bf1 = *(const float4*)(bfp + n0 + tx * 8 + 4);
  for (int i = 0; i < 8; i++) {
    size_t off = (size_t)(m0 + ty * 8 + i) * DIMN + n0 + tx * 8;
    float4 r0 = *(const float4*)(modp + off);
    float4 r1 = *(const float4*)(modp + off + 4);
    float4 o0, o1;
    o0.x = r0.x + eluf(acc[i][0] + bf0.x);
    o0.y = r0.y + eluf(acc[i][1] + bf0.y);
    o0.z = r0.z + eluf(acc[i][2] + bf0.z);
    o0.w = r0.w + eluf(acc[i][3] + bf0.w);
    o1.x = r1.x + eluf(acc[i][4] + bf1.x);
    o1.y = r1.y + eluf(acc[i][5] + bf1.y);
    o1.z = r1.z + eluf(acc[i][6] + bf1.z);
    o1.w = r1.w + eluf(acc[i][7] + bf1.w);
    *(float4*)(out + off) = o0;
    *(float4*)(out + off + 4) = o1;
  }
}

extern "C" void kernel_launch(void* const* d_in, const int* in_sizes, int n_in, void* d_out,
                              int out_size, void* d_ws, size_t ws_size, hipStream_t stream) {
  (void)in_sizes;
  (void)n_in;
  (void)out_size;
  (void)ws_size;
  const float* x = (const float*)d_in[0];
  const float* W_in = (const float*)d_in[1];
  const float* gamma = (const float*)d_in[2];
  const float* beta = (const float*)d_in[3];
  const float* Wq = (const float*)d_in[4];
  const float* Wk = (const float*)d_in[5];
  const float* Wv = (const float*)d_in[6];
  const float* Wf = (const float*)d_in[7];
  const float* bf = (const float*)d_in[8];
  float* out = (float*)d_out;

  char* ws = (char*)d_ws;
  float* mod = (float*)ws;                                // 32 MB fp32 [8192,1024]
  u16* qb = (u16*)(ws + 32ull * 1024 * 1024);             // 16 MB bf16 [B,H,S,E]
  u16* kb = (u16*)(ws + 48ull * 1024 * 1024);             // 16 MB
  u16* vb = (u16*)(ws + 64ull * 1024 * 1024);             // 16 MB
  float* mean2 = (float*)(ws + 80ull * 1024 * 1024);      // 32 KB
  float* rstd2 = mean2 + NROWS;                           // 32 KB

  dim3 gg(DIMN / BN, NROWS / BM);  // (8, 64)
  gemm_xwin<<<gg, 256, 0, stream>>>(x, W_in, mod);
  ln_qkv<<<NROWS / 4, 256, 0, stream>>>(mod, gamma, beta, Wq, Wk, Wv, qb, kb, vb);
  attn<<<dim3(SEQ / 32, NB * NHEAD), 256, 0, stream>>>(qb, kb, vb, mod);
  row_stats<<<NROWS, 256, 0, stream>>>(mod, mean2, rstd2);
  gemm_ffn<<<gg, 256, 0, stream>>>(mod, Wf, bf, gamma, beta, mean2, rstd2, out);
}

// Round 2
// 1175.594 us; speedup vs baseline: 2.7880x; 2.7880x over previous
//
#include <hip/hip_runtime.h>
#include <hip/hip_bf16.h>

#define DIMN 1024
#define NHEAD 8
#define ESPL 128
#define NB 4
#define SEQ 2048
#define NROWS (NB * SEQ)
#define LNEPS 1e-6f

typedef unsigned short u16;
typedef unsigned int u32;
typedef __attribute__((ext_vector_type(8))) short short8;
typedef __attribute__((ext_vector_type(4))) float f32x4;

__device__ __forceinline__ u16 f2bf(float f) {
  u32 u = __float_as_uint(f);
  u += 0x7FFFu + ((u >> 16) & 1u);  // round-to-nearest-even
  return (u16)(u >> 16);
}

__device__ __forceinline__ float eluf(float x) { return x > 0.f ? x : expm1f(x); }

// 256-thread block sum (4 waves). rb is shared float[8].
__device__ __forceinline__ float block_sum256(float v, float* rb, int t) {
#pragma unroll
  for (int o = 32; o > 0; o >>= 1) v += __shfl_down(v, o);
  __syncthreads();  // protect rb from previous use
  if ((t & 63) == 0) rb[t >> 6] = v;
  __syncthreads();
  return rb[0] + rb[1] + rb[2] + rb[3];
}

// ---------------- GEMM1: mod = x @ W_in  (8192x1024 @ 1024x1024) ----------------
#define BM 128
#define BN 128
#define BK 8

__global__ __launch_bounds__(256) void gemm_xwin(const float* __restrict__ A,
                                                 const float* __restrict__ B,
                                                 float* __restrict__ C) {
  __shared__ float As[BK][BM + 4];
  __shared__ float Bs[BK][BN + 4];
  const int t = threadIdx.x;
  const int m0 = blockIdx.y * BM;
  const int n0 = blockIdx.x * BN;
  const int lm = t >> 1;
  const int lk = (t & 1) << 2;
  const int bk = t >> 5;
  const int bn = (t & 31) << 2;
  const int tx = t & 15;
  const int ty = t >> 4;
  const float* Ap = A + (size_t)(m0 + lm) * DIMN + lk;
  const float* Bp = B + (size_t)bk * DIMN + n0 + bn;
  float acc[8][8] = {};
  for (int kt = 0; kt < DIMN; kt += BK) {
    float4 av = *(const float4*)(Ap + kt);
    float4 bv = *(const float4*)(Bp + (size_t)kt * DIMN);
    As[lk + 0][lm] = av.x;
    As[lk + 1][lm] = av.y;
    As[lk + 2][lm] = av.z;
    As[lk + 3][lm] = av.w;
    *(float4*)&Bs[bk][bn] = bv;
    __syncthreads();
#pragma unroll
    for (int k2 = 0; k2 < BK; k2++) {
      float a[8], b[8];
      *(float4*)(a + 0) = *(const float4*)&As[k2][ty * 8 + 0];
      *(float4*)(a + 4) = *(const float4*)&As[k2][ty * 8 + 4];
      *(float4*)(b + 0) = *(const float4*)&Bs[k2][tx * 8 + 0];
      *(float4*)(b + 4) = *(const float4*)&Bs[k2][tx * 8 + 4];
#pragma unroll
      for (int i = 0; i < 8; i++)
#pragma unroll
        for (int j = 0; j < 8; j++) acc[i][j] += a[i] * b[j];
    }
    __syncthreads();
  }
  for (int i = 0; i < 8; i++) {
    float* Cp = C + (size_t)(m0 + ty * 8 + i) * DIMN + n0 + tx * 8;
    *(float4*)(Cp + 0) = make_float4(acc[i][0], acc[i][1], acc[i][2], acc[i][3]);
    *(float4*)(Cp + 4) = make_float4(acc[i][4], acc[i][5], acc[i][6], acc[i][7]);
  }
}

// ------- LN1 fused with per-head QKV projections; 4 rows per block -------
// q,k written [b,h,s,e]; v written TRANSPOSED [b,h,e,s] for MFMA B-frag reads.
__global__ __launch_bounds__(256) void ln_qkv(const float* __restrict__ modp,
                                              const float* __restrict__ gamma,
                                              const float* __restrict__ beta,
                                              const float* __restrict__ Wq,
                                              const float* __restrict__ Wk,
                                              const float* __restrict__ Wv,
                                              u16* __restrict__ qo, u16* __restrict__ ko,
                                              u16* __restrict__ vto) {
  __shared__ float hs[4][DIMN];
  __shared__ float rb[8];
  const int t = threadIdx.x;
  const int row0 = blockIdx.x << 2;
  for (int r = 0; r < 4; r++) {
    const float* xr = modp + (size_t)(row0 + r) * DIMN;
    float4 xv = ((const float4*)xr)[t];
    float s = xv.x + xv.y + xv.z + xv.w;
    s = block_sum256(s, rb, t);
    float mean = s * (1.f / DIMN);
    float dx = xv.x - mean, dy = xv.y - mean, dz = xv.z - mean, dw = xv.w - mean;
    float sq = block_sum256(dx * dx + dy * dy + dz * dz + dw * dw, rb, t);
    float rstd = rsqrtf(sq * (1.f / DIMN) + LNEPS);
    float4 gv = ((const float4*)gamma)[t];
    float4 bv = ((const float4*)beta)[t];
    float* hr = hs[r] + (t << 2);
    hr[0] = dx * rstd * gv.x + bv.x;
    hr[1] = dy * rstd * gv.y + bv.y;
    hr[2] = dz * rstd * gv.z + bv.z;
    hr[3] = dw * rstd * gv.w + bv.w;
  }
  __syncthreads();
  const float* Ws[3] = {Wq, Wk, Wv};
  for (int mI = 0; mI < 3; mI++) {
    const float* W = Ws[mI];
    for (int p = 0; p < 4; p++) {
      const int oi = t + (p << 8);
      const int hh = oi >> 7;
      const int e = oi & 127;
      const float* w = W + ((size_t)hh << 14) + e;
      const float* h0 = hs[0] + (hh << 7);
      const float* h1 = hs[1] + (hh << 7);
      const float* h2 = hs[2] + (hh << 7);
      const float* h3 = hs[3] + (hh << 7);
      float a0 = 0.f, a1 = 0.f, a2 = 0.f, a3 = 0.f;
#pragma unroll 16
      for (int d = 0; d < 128; d++) {
        float wvv = w[(size_t)d << 7];
        a0 += h0[d] * wvv;
        a1 += h1[d] * wvv;
        a2 += h2[d] * wvv;
        a3 += h3[d] * wvv;
      }
      const int bb = row0 >> 11;
      if (mI < 2) {
        u16* o = (mI == 0) ? qo : ko;
        float vals[4] = {a0, a1, a2, a3};
        for (int r = 0; r < 4; r++) {
          int rowr = row0 + r;
          size_t idx = (((size_t)bb * NHEAD + hh) * SEQ + (rowr & 2047)) * ESPL + e;
          o[idx] = f2bf(vals[r]);
        }
      } else {
        // vt[b,h,e,s]: 4 consecutive seq rows -> one 8B store
        size_t idx = (((size_t)bb * NHEAD + hh) * ESPL + e) * SEQ + (row0 & 2047);
        ushort4 pk;
        pk.x = f2bf(a0);
        pk.y = f2bf(a1);
        pk.z = f2bf(a2);
        pk.w = f2bf(a3);
        *(ushort4*)(vto + idx) = pk;
      }
    }
  }
}

// ------- MFMA flash attention: 64-row q-tile per block, 64-col k-tiles -------
// q,k: [b,h,s,e] bf16; vt: [b,h,e,s] bf16. Adds softmax(QK^T)V into mod.
#define KP 136  // K LDS pitch (bf16 elems, 16B-aligned rows, 2-way banks max)
#define VP 72   // Vt LDS pitch
#define SP 68   // S LDS pitch (f32, float4-aligned)
#define PP 72   // P LDS pitch (bf16)

__global__ __launch_bounds__(256) void attn_mfma(const u16* __restrict__ q,
                                                 const u16* __restrict__ kk,
                                                 const u16* __restrict__ vt,
                                                 float* __restrict__ modp) {
  __shared__ u16 Ks[64 * KP];     // 17408 B
  __shared__ u16 Vs[128 * VP];    // 18432 B
  __shared__ float Ss[64 * SP];   // 17408 B
  __shared__ u16 Ps[64 * PP];     // 9216 B
  __shared__ float alpha_s[64];
  __shared__ float l_s[64];
  const int t = threadIdx.x;
  const int w = t >> 6, lane = t & 63, quad = lane >> 4, l16 = lane & 15;
  const int qt = blockIdx.x;  // 0..31
  const int bh = blockIdx.y;  // 0..31
  const size_t qkbase = (size_t)bh * SEQ * ESPL;

  // Q A-frags for this wave's 16 q-rows, all 128 E (4 k-chunks of 32)
  short8 qf[4];
  {
    const u16* qrow = q + qkbase + (size_t)(qt * 64 + w * 16 + l16) * ESPL + quad * 8;
#pragma unroll
    for (int kc = 0; kc < 4; kc++) qf[kc] = *(const short8*)(qrow + kc * 32);
  }

  float m_r = -1e30f, l_r = 0.f;
  f32x4 oacc[8];
#pragma unroll
  for (int n = 0; n < 8; n++) oacc[n] = (f32x4){0.f, 0.f, 0.f, 0.f};
  const int sr = w * 16 + (lane >> 2);  // softmax: row owned by this thread
  const int sm = lane & 3;              // quarter (16 cols)

  for (int kt = 0; kt < SEQ / 64; kt++) {
    __syncthreads();  // prev PV done before restaging
    {
      const u16* kg = kk + qkbase + (size_t)kt * 64 * ESPL;
      const u16* vg = vt + qkbase + (size_t)kt * 64;
#pragma unroll
      for (int i = 0; i < 4; i++) {
        int p = t + (i << 8);
        int r = p >> 4, c = (p & 15) << 3;
        *(uint4*)(Ks + r * KP + c) = *(const uint4*)(kg + r * ESPL + c);
      }
#pragma unroll
      for (int i = 0; i < 4; i++) {
        int p = t + (i << 8);
        int e = p >> 3, c = (p & 7) << 3;
        *(uint4*)(Vs + e * VP + c) = *(const uint4*)(vg + (size_t)e * SEQ + c);
      }
    }
    __syncthreads();
    // QK^T: wave w computes S rows [16w,16w+16) x 64 cols
#pragma unroll
    for (int c = 0; c < 4; c++) {
      f32x4 sacc = {0.f, 0.f, 0.f, 0.f};
#pragma unroll
      for (int kc = 0; kc < 4; kc++) {
        short8 bf = *(const short8*)(Ks + (c * 16 + l16) * KP + kc * 32 + quad * 8);
        sacc = __builtin_amdgcn_mfma_f32_16x16x32_bf16(qf[kc], bf, sacc, 0, 0, 0);
      }
#pragma unroll
      for (int r = 0; r < 4; r++)
        Ss[(w * 16 + quad * 4 + r) * SP + c * 16 + l16] = sacc[r];
    }
    __syncthreads();
    // online softmax: 4 threads per row, 16 cols each
    {
      const float* srow = Ss + sr * SP + sm * 16;
      float sv[16];
#pragma unroll
      for (int j = 0; j < 4; j++) *(float4*)(sv + j * 4) = *(const float4*)(srow + j * 4);
      float mx = sv[0];
#pragma unroll
      for (int j = 1; j < 16; j++) mx = fmaxf(mx, sv[j]);
      mx = fmaxf(mx, __shfl_xor(mx, 1));
      mx = fmaxf(mx, __shfl_xor(mx, 2));
      float mnew = fmaxf(m_r, mx);
      float al = __expf(m_r - mnew);
      float sum = 0.f;
      u32 pk[8];
#pragma unroll
      for (int j = 0; j < 8; j++) {
        float p0 = __expf(sv[2 * j] - mnew);
        float p1 = __expf(sv[2 * j + 1] - mnew);
        sum += p0 + p1;
        pk[j] = (u32)f2bf(p0) | ((u32)f2bf(p1) << 16);
      }
      sum += __shfl_xor(sum, 1);
      sum += __shfl_xor(sum, 2);
      l_r = l_r * al + sum;
      m_r = mnew;
      if (sm == 0) alpha_s[sr] = al;
      u16* prow = Ps + sr * PP + sm * 16;
      *(uint4*)(prow + 0) = make_uint4(pk[0], pk[1], pk[2], pk[3]);
      *(uint4*)(prow + 8) = make_uint4(pk[4], pk[5], pk[6], pk[7]);
    }
    __syncthreads();
    // rescale O, then P @ V via MFMA
    {
      float alr[4];
#pragma unroll
      for (int r = 0; r < 4; r++) alr[r] = alpha_s[w * 16 + quad * 4 + r];
#pragma unroll
      for (int n = 0; n < 8; n++)
#pragma unroll
        for (int r = 0; r < 4; r++) oacc[n][r] *= alr[r];
      short8 pa0 = *(const short8*)(Ps + (w * 16 + l16) * PP + quad * 8);
      short8 pa1 = *(const short8*)(Ps + (w * 16 + l16) * PP + 32 + quad * 8);
#pragma unroll
      for (int n = 0; n < 8; n++) {
        short8 bv0 = *(const short8*)(Vs + (n * 16 + l16) * VP + quad * 8);
        short8 bv1 = *(const short8*)(Vs + (n * 16 + l16) * VP + 32 + quad * 8);
        oacc[n] = __builtin_amdgcn_mfma_f32_16x16x32_bf16(pa0, bv0, oacc[n], 0, 0, 0);
        oacc[n] = __builtin_amdgcn_mfma_f32_16x16x32_bf16(pa1, bv1, oacc[n], 0, 0, 0);
      }
    }
  }
  if (sm == 0) l_s[sr] = l_r;
  __syncthreads();
  float linv[4];
#pragma unroll
  for (int r = 0; r < 4; r++) linv[r] = 1.f / l_s[w * 16 + quad * 4 + r];
  const int b = bh >> 3, hh = bh & 7;
  for (int r = 0; r < 4; r++) {
    int qrow = qt * 64 + w * 16 + quad * 4 + r;
    float* mp = modp + ((size_t)(b * SEQ + qrow)) * DIMN + hh * ESPL + l16;
#pragma unroll
    for (int n = 0; n < 8; n++) mp[n * 16] += oacc[n][r] * linv[r];
  }
}

// ------- per-row mean / rstd of (mod + attention residual) -------
__global__ __launch_bounds__(256) void row_stats(const float* __restrict__ modp,
                                                 float* __restrict__ mean2,
                                                 float* __restrict__ rstd2) {
  __shared__ float rb[8];
  const int row = blockIdx.x;
  const int t = threadIdx.x;
  float4 xv = ((const float4*)(modp + (size_t)row * DIMN))[t];
  float s = block_sum256(xv.x + xv.y + xv.z + xv.w, rb, t);
  float mean = s * (1.f / DIMN);
  float dx = xv.x - mean, dy = xv.y - mean, dz = xv.z - mean, dw = xv.w - mean;
  float sq = block_sum256(dx * dx + dy * dy + dz * dz + dw * dw, rb, t);
  if (t == 0) {
    mean2[row] = mean;
    rstd2[row] = rsqrtf(sq * (1.f / DIMN) + LNEPS);
  }
}

// ------- GEMM2: out = mod + elu(LN2(mod) @ Wf + bf), LN fused in A-load -------
__global__ __launch_bounds__(256) void gemm_ffn(const float* __restrict__ modp,
                                                const float* __restrict__ Wf,
                                                const float* __restrict__ bfp,
                                                const float* __restrict__ gamma,
                                                const float* __restrict__ beta,
                                                const float* __restrict__ mean2,
                                                const float* __restrict__ rstd2,
                                                float* __restrict__ out) {
  __shared__ float As[BK][BM + 4];
  __shared__ float Bs[BK][BN + 4];
  const int t = threadIdx.x;
  const int m0 = blockIdx.y * BM;
  const int n0 = blockIdx.x * BN;
  const int lm = t >> 1;
  const int lk = (t & 1) << 2;
  const int bk = t >> 5;
  const int bn = (t & 31) << 2;
  const int tx = t & 15;
  const int ty = t >> 4;
  const int am = m0 + lm;
  const float mu = mean2[am];
  const float rs = rstd2[am];
  const float* Ap = modp + (size_t)am * DIMN + lk;
  const float* Bp = Wf + (size_t)bk * DIMN + n0 + bn;
  float acc[8][8] = {};
  for (int kt = 0; kt < DIMN; kt += BK) {
    float4 av = *(const float4*)(Ap + kt);
    float4 gv = *(const float4*)(gamma + kt + lk);
    float4 btv = *(const float4*)(beta + kt + lk);
    float4 bv = *(const float4*)(Bp + (size_t)kt * DIMN);
    As[lk + 0][lm] = (av.x - mu) * rs * gv.x + btv.x;
    As[lk + 1][lm] = (av.y - mu) * rs * gv.y + btv.y;
    As[lk + 2][lm] = (av.z - mu) * rs * gv.z + btv.z;
    As[lk + 3][lm] = (av.w - mu) * rs * gv.w + btv.w;
    *(float4*)&Bs[bk][bn] = bv;
    __syncthreads();
#pragma unroll
    for (int k2 = 0; k2 < BK; k2++) {
      float a[8], b[8];
      *(float4*)(a + 0) = *(const float4*)&As[k2][ty * 8 + 0];
      *(float4*)(a + 4) = *(const float4*)&As[k2][ty * 8 + 4];
      *(float4*)(b + 0) = *(const float4*)&Bs[k2][tx * 8 + 0];
      *(float4*)(b + 4) = *(const float4*)&Bs[k2][tx * 8 + 4];
#pragma unroll
      for (int i = 0; i < 8; i++)
#pragma unroll
        for (int j = 0; j < 8; j++) acc[i][j] += a[i] * b[j];
    }
    __syncthreads();
  }
  const float4 bf0 = *(const float4*)(bfp + n0 + tx * 8 + 0);
  const float4 bf1 = *(const float4*)(bfp + n0 + tx * 8 + 4);
  for (int i = 0; i < 8; i++) {
    size_t off = (size_t)(m0 + ty * 8 + i) * DIMN + n0 + tx * 8;
    float4 r0 = *(const float4*)(modp + off);
    float4 r1 = *(const float4*)(modp + off + 4);
    float4 o0, o1;
    o0.x = r0.x + eluf(acc[i][0] + bf0.x);
    o0.y = r0.y + eluf(acc[i][1] + bf0.y);
    o0.z = r0.z + eluf(acc[i][2] + bf0.z);
    o0.w = r0.w + eluf(acc[i][3] + bf0.w);
    o1.x = r1.x + eluf(acc[i][4] + bf1.x);
    o1.y = r1.y + eluf(acc[i][5] + bf1.y);
    o1.z = r1.z + eluf(acc[i][6] + bf1.z);
    o1.w = r1.w + eluf(acc[i][7] + bf1.w);
    *(float4*)(out + off) = o0;
    *(float4*)(out + off + 4) = o1;
  }
}

extern "C" void kernel_launch(void* const* d_in, const int* in_sizes, int n_in, void* d_out,
                              int out_size, void* d_ws, size_t ws_size, hipStream_t stream) {
  (void)in_sizes;
  (void)n_in;
  (void)out_size;
  (void)ws_size;
  const float* x = (const float*)d_in[0];
  const float* W_in = (const float*)d_in[1];
  const float* gamma = (const float*)d_in[2];
  const float* beta = (const float*)d_in[3];
  const float* Wq = (const float*)d_in[4];
  const float* Wk = (const float*)d_in[5];
  const float* Wv = (const float*)d_in[6];
  const float* Wf = (const float*)d_in[7];
  const float* bf = (const float*)d_in[8];
  float* out = (float*)d_out;

  char* ws = (char*)d_ws;
  float* mod = (float*)ws;                            // 32 MB fp32 [8192,1024]
  u16* qb = (u16*)(ws + 32ull * 1024 * 1024);         // 16 MB bf16 [B,H,S,E]
  u16* kb = (u16*)(ws + 48ull * 1024 * 1024);         // 16 MB bf16 [B,H,S,E]
  u16* vtb = (u16*)(ws + 64ull * 1024 * 1024);        // 16 MB bf16 [B,H,E,S] (transposed)
  float* mean2 = (float*)(ws + 80ull * 1024 * 1024);  // 32 KB
  float* rstd2 = mean2 + NROWS;                       // 32 KB

  dim3 gg(DIMN / BN, NROWS / BM);  // (8, 64)
  gemm_xwin<<<gg, 256, 0, stream>>>(x, W_in, mod);
  ln_qkv<<<NROWS / 4, 256, 0, stream>>>(mod, gamma, beta, Wq, Wk, Wv, qb, kb, vtb);
  attn_mfma<<<dim3(SEQ / 64, NB * NHEAD), 256, 0, stream>>>(qb, kb, vtb, mod);
  row_stats<<<NROWS, 256, 0, stream>>>(mod, mean2, rstd2);
  gemm_ffn<<<gg, 256, 0, stream>>>(mod, Wf, bf, gamma, beta, mean2, rstd2, out);
}

// Round 3
// 407.321 us; speedup vs baseline: 8.0466x; 2.8862x over previous
//
#include <hip/hip_runtime.h>
#include <hip/hip_bf16.h>

#define DIMN 1024
#define NHEAD 8
#define ESPL 128
#define NB 4
#define SEQ 2048
#define NROWS (NB * SEQ)
#define LNEPS 1e-6f

typedef unsigned short u16;
typedef unsigned int u32;
typedef __attribute__((ext_vector_type(8))) short short8;
typedef __attribute__((ext_vector_type(4))) float f32x4;

__device__ __forceinline__ u16 f2bf(float f) {
  u32 u = __float_as_uint(f);
  u += 0x7FFFu + ((u >> 16) & 1u);  // round-to-nearest-even
  return (u16)(u >> 16);
}

__device__ __forceinline__ uint2 pack4bf(float4 v) {
  uint2 r;
  r.x = (u32)f2bf(v.x) | ((u32)f2bf(v.y) << 16);
  r.y = (u32)f2bf(v.z) | ((u32)f2bf(v.w) << 16);
  return r;
}

__device__ __forceinline__ float eluf(float x) { return x > 0.f ? x : expm1f(x); }

// 256-thread block sum (4 waves). rb is shared float[8].
__device__ __forceinline__ float block_sum256(float v, float* rb, int t) {
#pragma unroll
  for (int o = 32; o > 0; o >>= 1) v += __shfl_down(v, o);
  __syncthreads();  // protect rb from previous use
  if ((t & 63) == 0) rb[t >> 6] = v;
  __syncthreads();
  return rb[0] + rb[1] + rb[2] + rb[3];
}

// ------- weight transpose + fp32->bf16: dst[n*K+k] = bf16(src[k*N+n]) -------
// grid: (N/64, K/64, nmat); hstride = per-matrix element count (0 if single)
__global__ __launch_bounds__(256) void wtrans(const float* __restrict__ src,
                                              u16* __restrict__ dst, int K, int N,
                                              int hstride) {
  __shared__ u16 tl[64][68];
  const int t = threadIdx.x;
  const int n0 = blockIdx.x * 64, k0 = blockIdx.y * 64;
  src += (size_t)blockIdx.z * hstride;
  dst += (size_t)blockIdx.z * hstride;
  const int r = t >> 2;
#pragma unroll
  for (int j = 0; j < 4; j++) {
    int f = (t & 3) + j * 4;  // float4 index 0..15
    float4 v = *(const float4*)(src + (size_t)(k0 + r) * N + n0 + f * 4);
    *(uint2*)&tl[r][f * 4] = pack4bf(v);
  }
  __syncthreads();
#pragma unroll
  for (int j = 0; j < 4; j++) {
    int f = (t & 3) + j * 4;  // k-chunk of 4
    ushort4 o;
    o.x = tl[f * 4 + 0][r];
    o.y = tl[f * 4 + 1][r];
    o.z = tl[f * 4 + 2][r];
    o.w = tl[f * 4 + 3][r];
    *(ushort4*)(dst + (size_t)(n0 + r) * K + k0 + f * 4) = o;
  }
}

// ------- per-row mean / rstd -------
__global__ __launch_bounds__(256) void row_stats(const float* __restrict__ modp,
                                                 float* __restrict__ meanp,
                                                 float* __restrict__ rstdp) {
  __shared__ float rb[8];
  const int row = blockIdx.x;
  const int t = threadIdx.x;
  float4 xv = ((const float4*)(modp + (size_t)row * DIMN))[t];
  float s = block_sum256(xv.x + xv.y + xv.z + xv.w, rb, t);
  float mean = s * (1.f / DIMN);
  float dx = xv.x - mean, dy = xv.y - mean, dz = xv.z - mean, dw = xv.w - mean;
  float sq = block_sum256(dx * dx + dy * dy + dz * dz + dw * dw, rb, t);
  if (t == 0) {
    meanp[row] = mean;
    rstdp[row] = rsqrtf(sq * (1.f / DIMN) + LNEPS);
  }
}

// ------- bf16 MFMA GEMM, 128x128 tile, BK=64, K=1024 -------
// MODE 0: C = A @ Bt^T (A fp32 cast to bf16), C fp32
// MODE 1: C = resid + elu(LN(A) @ Bt^T + bias)   (LN via mean/rstd/gamma/beta)
#define GP 72  // LDS pitch (bf16)

template <int MODE>
__global__ __launch_bounds__(256) void gemm_mfma(
    const float* __restrict__ A, const u16* __restrict__ Bt, const float* __restrict__ resid,
    const float* __restrict__ bias, const float* __restrict__ gamma,
    const float* __restrict__ beta, const float* __restrict__ meanp,
    const float* __restrict__ rstdp, float* __restrict__ C) {
  __shared__ u16 Asl[128 * GP];
  __shared__ u16 Bsl[128 * GP];
  const int t = threadIdx.x;
  const int w = t >> 6, lane = t & 63, quad = lane >> 4, l16 = lane & 15;
  const int wm = w & 1, wn = w >> 1;
  const int m0 = blockIdx.y * 128, n0 = blockIdx.x * 128;
  const int sr8 = t >> 3, sf8 = t & 7;
  float mu[4], rsd[4];
  if (MODE == 1) {
#pragma unroll
    for (int p = 0; p < 4; p++) {
      mu[p] = meanp[m0 + sr8 + 32 * p];
      rsd[p] = rstdp[m0 + sr8 + 32 * p];
    }
  }
  f32x4 acc[4][4];
#pragma unroll
  for (int mt = 0; mt < 4; mt++)
#pragma unroll
    for (int nt = 0; nt < 4; nt++) acc[mt][nt] = (f32x4){0.f, 0.f, 0.f, 0.f};

  for (int kt = 0; kt < DIMN; kt += 64) {
    __syncthreads();  // prev compute done before restaging
    // A-tile: 128 rows x 64 k fp32 -> bf16; 8 thr/row, 2 float4 each, 4 passes
#pragma unroll
    for (int p = 0; p < 4; p++) {
      int r = sr8 + 32 * p;
      const float* ap = A + (size_t)(m0 + r) * DIMN + kt;
#pragma unroll
      for (int j = 0; j < 2; j++) {
        int f = sf8 + j * 8;  // 0..15
        float4 v = *(const float4*)(ap + f * 4);
        if (MODE == 1) {
          float4 g = *(const float4*)(gamma + kt + f * 4);
          float4 bb = *(const float4*)(beta + kt + f * 4);
          v.x = (v.x - mu[p]) * rsd[p] * g.x + bb.x;
          v.y = (v.y - mu[p]) * rsd[p] * g.y + bb.y;
          v.z = (v.z - mu[p]) * rsd[p] * g.z + bb.z;
          v.w = (v.w - mu[p]) * rsd[p] * g.w + bb.w;
        }
        *(uint2*)(Asl + r * GP + f * 4) = pack4bf(v);
      }
    }
    // B-tile: 128 n x 64 k bf16; 8 thr/row, 1 uint4 each, 4 passes
#pragma unroll
    for (int p = 0; p < 4; p++) {
      int r = sr8 + 32 * p;
      *(uint4*)(Bsl + r * GP + sf8 * 8) = *(const uint4*)(Bt + (size_t)(n0 + r) * DIMN + kt + sf8 * 8);
    }
    __syncthreads();
#pragma unroll
    for (int ks = 0; ks < 64; ks += 32) {
      short8 af[4], bfr[4];
#pragma unroll
      for (int mt = 0; mt < 4; mt++)
        af[mt] = *(const short8*)(Asl + (wm * 64 + mt * 16 + l16) * GP + ks + quad * 8);
#pragma unroll
      for (int nt = 0; nt < 4; nt++)
        bfr[nt] = *(const short8*)(Bsl + (wn * 64 + nt * 16 + l16) * GP + ks + quad * 8);
#pragma unroll
      for (int mt = 0; mt < 4; mt++)
#pragma unroll
        for (int nt = 0; nt < 4; nt++)
          acc[mt][nt] = __builtin_amdgcn_mfma_f32_16x16x32_bf16(af[mt], bfr[nt], acc[mt][nt], 0, 0, 0);
    }
  }
  // epilogue
#pragma unroll
  for (int mt = 0; mt < 4; mt++) {
#pragma unroll
    for (int r = 0; r < 4; r++) {
      int row = m0 + wm * 64 + mt * 16 + quad * 4 + r;
#pragma unroll
      for (int nt = 0; nt < 4; nt++) {
        int col = n0 + wn * 64 + nt * 16 + l16;
        size_t off = (size_t)row * DIMN + col;
        float v = acc[mt][nt][r];
        if (MODE == 0)
          C[off] = v;
        else
          C[off] = resid[off] + eluf(v + bias[col]);
      }
    }
  }
}

// ------- QKV: per (b,h), 128 s-rows x 128 e, K=128; LN1 fused in A-staging -------
#define QP 136

__global__ __launch_bounds__(256) void qkv_mfma(
    const float* __restrict__ modp, const u16* __restrict__ wqt, const u16* __restrict__ wkt,
    const u16* __restrict__ wvt, const float* __restrict__ gamma, const float* __restrict__ beta,
    const float* __restrict__ mean1, const float* __restrict__ rstd1, u16* __restrict__ qo,
    u16* __restrict__ ko, u16* __restrict__ vto) {
  __shared__ u16 Asl[128 * QP];
  __shared__ u16 Bsl[128 * QP];
  const int t = threadIdx.x;
  const int w = t >> 6, lane = t & 63, quad = lane >> 4, l16 = lane & 15;
  const int wm = w & 1, wn = w >> 1;
  const int s0 = blockIdx.x * 128;
  const int bh = blockIdx.y;
  const int b = bh >> 3, hh = bh & 7;
  const int sr8 = t >> 3, sf8 = t & 7;
  // stage A = LN1(mod[b, s0..s0+128, hh*128..hh*128+128]) as bf16
#pragma unroll
  for (int p = 0; p < 4; p++) {
    int r = sr8 + 32 * p;
    int rowg = b * SEQ + s0 + r;
    float mu = mean1[rowg], rsd = rstd1[rowg];
    const float* ap = modp + (size_t)rowg * DIMN + hh * ESPL;
#pragma unroll
    for (int j = 0; j < 4; j++) {
      int f = sf8 + j * 8;  // 0..31 float4s
      float4 v = *(const float4*)(ap + f * 4);
      float4 g = *(const float4*)(gamma + hh * ESPL + f * 4);
      float4 bb = *(const float4*)(beta + hh * ESPL + f * 4);
      v.x = (v.x - mu) * rsd * g.x + bb.x;
      v.y = (v.y - mu) * rsd * g.y + bb.y;
      v.z = (v.z - mu) * rsd * g.z + bb.z;
      v.w = (v.w - mu) * rsd * g.w + bb.w;
      *(uint2*)(Asl + r * QP + f * 4) = pack4bf(v);
    }
  }
  __syncthreads();
  // hoist A-frags: 4 k-steps x 4 m-tiles
  short8 afr[4][4];
#pragma unroll
  for (int k4 = 0; k4 < 4; k4++)
#pragma unroll
    for (int mt = 0; mt < 4; mt++)
      afr[k4][mt] = *(const short8*)(Asl + (wm * 64 + mt * 16 + l16) * QP + k4 * 32 + quad * 8);

  const u16* Ws[3] = {wqt, wkt, wvt};
  for (int mi = 0; mi < 3; mi++) {
    __syncthreads();  // prev compute's Bsl reads done
    const u16* wsrc = Ws[mi] + ((size_t)hh << 14);
#pragma unroll
    for (int p = 0; p < 4; p++) {
      int r = sr8 + 32 * p;
#pragma unroll
      for (int j = 0; j < 2; j++) {
        int f = sf8 + j * 8;
        *(uint4*)(Bsl + r * QP + f * 8) = *(const uint4*)(wsrc + r * ESPL + f * 8);
      }
    }
    __syncthreads();
    f32x4 acc[4][4];
#pragma unroll
    for (int mt = 0; mt < 4; mt++)
#pragma unroll
      for (int nt = 0; nt < 4; nt++) acc[mt][nt] = (f32x4){0.f, 0.f, 0.f, 0.f};
#pragma unroll
    for (int k4 = 0; k4 < 4; k4++) {
      short8 bfr[4];
#pragma unroll
      for (int nt = 0; nt < 4; nt++)
        bfr[nt] = *(const short8*)(Bsl + (wn * 64 + nt * 16 + l16) * QP + k4 * 32 + quad * 8);
#pragma unroll
      for (int mt = 0; mt < 4; mt++)
#pragma unroll
        for (int nt = 0; nt < 4; nt++)
          acc[mt][nt] = __builtin_amdgcn_mfma_f32_16x16x32_bf16(afr[k4][mt], bfr[nt], acc[mt][nt], 0, 0, 0);
    }
    if (mi < 2) {
      u16* o = (mi == 0) ? qo : ko;
#pragma unroll
      for (int mt = 0; mt < 4; mt++)
#pragma unroll
        for (int r = 0; r < 4; r++) {
          int s = s0 + wm * 64 + mt * 16 + quad * 4 + r;
#pragma unroll
          for (int nt = 0; nt < 4; nt++) {
            int e = wn * 64 + nt * 16 + l16;
            o[((size_t)bh * SEQ + s) * ESPL + e] = f2bf(acc[mt][nt][r]);
          }
        }
    } else {
#pragma unroll
      for (int mt = 0; mt < 4; mt++)
#pragma unroll
        for (int nt = 0; nt < 4; nt++) {
          int e = wn * 64 + nt * 16 + l16;
          int sbase = s0 + wm * 64 + mt * 16 + quad * 4;
          ushort4 pk;
          pk.x = f2bf(acc[mt][nt][0]);
          pk.y = f2bf(acc[mt][nt][1]);
          pk.z = f2bf(acc[mt][nt][2]);
          pk.w = f2bf(acc[mt][nt][3]);
          *(ushort4*)(vto + ((size_t)bh * ESPL + e) * SEQ + sbase) = pk;
        }
    }
  }
}

// ------- MFMA flash attention: 64-row q-tile per block, 64-col k-tiles -------
#define KP 136  // K LDS pitch (bf16 elems)
#define VP 72   // Vt LDS pitch
#define SP 68   // S LDS pitch (f32)
#define PP 72   // P LDS pitch (bf16)

__global__ __launch_bounds__(256) void attn_mfma(const u16* __restrict__ q,
                                                 const u16* __restrict__ kk,
                                                 const u16* __restrict__ vt,
                                                 float* __restrict__ modp) {
  __shared__ u16 Ks[64 * KP];
  __shared__ u16 Vs[128 * VP];
  __shared__ float Ss[64 * SP];
  __shared__ u16 Ps[64 * PP];
  __shared__ float alpha_s[64];
  __shared__ float l_s[64];
  const int t = threadIdx.x;
  const int w = t >> 6, lane = t & 63, quad = lane >> 4, l16 = lane & 15;
  const int qt = blockIdx.x;  // 0..31
  const int bh = blockIdx.y;  // 0..31
  const size_t qkbase = (size_t)bh * SEQ * ESPL;

  short8 qf[4];
  {
    const u16* qrow = q + qkbase + (size_t)(qt * 64 + w * 16 + l16) * ESPL + quad * 8;
#pragma unroll
    for (int kc = 0; kc < 4; kc++) qf[kc] = *(const short8*)(qrow + kc * 32);
  }

  float m_r = -1e30f, l_r = 0.f;
  f32x4 oacc[8];
#pragma unroll
  for (int n = 0; n < 8; n++) oacc[n] = (f32x4){0.f, 0.f, 0.f, 0.f};
  const int sr = w * 16 + (lane >> 2);
  const int sm = lane & 3;

  for (int kt = 0; kt < SEQ / 64; kt++) {
    __syncthreads();
    {
      const u16* kg = kk + qkbase + (size_t)kt * 64 * ESPL;
      const u16* vg = vt + qkbase + (size_t)kt * 64;
#pragma unroll
      for (int i = 0; i < 4; i++) {
        int p = t + (i << 8);
        int r = p >> 4, c = (p & 15) << 3;
        *(uint4*)(Ks + r * KP + c) = *(const uint4*)(kg + r * ESPL + c);
      }
#pragma unroll
      for (int i = 0; i < 4; i++) {
        int p = t + (i << 8);
        int e = p >> 3, c = (p & 7) << 3;
        *(uint4*)(Vs + e * VP + c) = *(const uint4*)(vg + (size_t)e * SEQ + c);
      }
    }
    __syncthreads();
#pragma unroll
    for (int c = 0; c < 4; c++) {
      f32x4 sacc = {0.f, 0.f, 0.f, 0.f};
#pragma unroll
      for (int kc = 0; kc < 4; kc++) {
        short8 bf = *(const short8*)(Ks + (c * 16 + l16) * KP + kc * 32 + quad * 8);
        sacc = __builtin_amdgcn_mfma_f32_16x16x32_bf16(qf[kc], bf, sacc, 0, 0, 0);
      }
#pragma unroll
      for (int r = 0; r < 4; r++)
        Ss[(w * 16 + quad * 4 + r) * SP + c * 16 + l16] = sacc[r];
    }
    __syncthreads();
    {
      const float* srow = Ss + sr * SP + sm * 16;
      float sv[16];
#pragma unroll
      for (int j = 0; j < 4; j++) *(float4*)(sv + j * 4) = *(const float4*)(srow + j * 4);
      float mx = sv[0];
#pragma unroll
      for (int j = 1; j < 16; j++) mx = fmaxf(mx, sv[j]);
      mx = fmaxf(mx, __shfl_xor(mx, 1));
      mx = fmaxf(mx, __shfl_xor(mx, 2));
      float mnew = fmaxf(m_r, mx);
      float al = __expf(m_r - mnew);
      float sum = 0.f;
      u32 pk[8];
#pragma unroll
      for (int j = 0; j < 8; j++) {
        float p0 = __expf(sv[2 * j] - mnew);
        float p1 = __expf(sv[2 * j + 1] - mnew);
        sum += p0 + p1;
        pk[j] = (u32)f2bf(p0) | ((u32)f2bf(p1) << 16);
      }
      sum += __shfl_xor(sum, 1);
      sum += __shfl_xor(sum, 2);
      l_r = l_r * al + sum;
      m_r = mnew;
      if (sm == 0) alpha_s[sr] = al;
      u16* prow = Ps + sr * PP + sm * 16;
      *(uint4*)(prow + 0) = make_uint4(pk[0], pk[1], pk[2], pk[3]);
      *(uint4*)(prow + 8) = make_uint4(pk[4], pk[5], pk[6], pk[7]);
    }
    __syncthreads();
    {
      float alr[4];
#pragma unroll
      for (int r = 0; r < 4; r++) alr[r] = alpha_s[w * 16 + quad * 4 + r];
#pragma unroll
      for (int n = 0; n < 8; n++)
#pragma unroll
        for (int r = 0; r < 4; r++) oacc[n][r] *= alr[r];
      short8 pa0 = *(const short8*)(Ps + (w * 16 + l16) * PP + quad * 8);
      short8 pa1 = *(const short8*)(Ps + (w * 16 + l16) * PP + 32 + quad * 8);
#pragma unroll
      for (int n = 0; n < 8; n++) {
        short8 bv0 = *(const short8*)(Vs + (n * 16 + l16) * VP + quad * 8);
        short8 bv1 = *(const short8*)(Vs + (n * 16 + l16) * VP + 32 + quad * 8);
        oacc[n] = __builtin_amdgcn_mfma_f32_16x16x32_bf16(pa0, bv0, oacc[n], 0, 0, 0);
        oacc[n] = __builtin_amdgcn_mfma_f32_16x16x32_bf16(pa1, bv1, oacc[n], 0, 0, 0);
      }
    }
  }
  if (sm == 0) l_s[sr] = l_r;
  __syncthreads();
  float linv[4];
#pragma unroll
  for (int r = 0; r < 4; r++) linv[r] = 1.f / l_s[w * 16 + quad * 4 + r];
  const int b = bh >> 3, hh = bh & 7;
  for (int r = 0; r < 4; r++) {
    int qrow = qt * 64 + w * 16 + quad * 4 + r;
    float* mp = modp + ((size_t)(b * SEQ + qrow)) * DIMN + hh * ESPL + l16;
#pragma unroll
    for (int n = 0; n < 8; n++) mp[n * 16] += oacc[n][r] * linv[r];
  }
}

extern "C" void kernel_launch(void* const* d_in, const int* in_sizes, int n_in, void* d_out,
                              int out_size, void* d_ws, size_t ws_size, hipStream_t stream) {
  (void)in_sizes;
  (void)n_in;
  (void)out_size;
  (void)ws_size;
  const float* x = (const float*)d_in[0];
  const float* W_in = (const float*)d_in[1];
  const float* gamma = (const float*)d_in[2];
  const float* beta = (const float*)d_in[3];
  const float* Wq = (const float*)d_in[4];
  const float* Wk = (const float*)d_in[5];
  const float* Wv = (const float*)d_in[6];
  const float* Wf = (const float*)d_in[7];
  const float* bf = (const float*)d_in[8];
  float* out = (float*)d_out;

  char* ws = (char*)d_ws;
  const size_t MB = 1024ull * 1024;
  float* mod = (float*)ws;                    // 32 MB fp32 [8192,1024]
  u16* qb = (u16*)(ws + 32 * MB);             // 16 MB bf16 [B,H,S,E]
  u16* kb = (u16*)(ws + 48 * MB);             // 16 MB bf16 [B,H,S,E]
  u16* vtb = (u16*)(ws + 64 * MB);            // 16 MB bf16 [B,H,E,S]
  float* mean1 = (float*)(ws + 80 * MB);      // 4 x 32 KB stats
  float* rstd1 = mean1 + NROWS;
  float* mean2 = rstd1 + NROWS;
  float* rstd2 = mean2 + NROWS;
  u16* wqt = (u16*)(ws + 80 * MB + 128 * 1024);  // 3 x 256 KB per-head [h][e][d]
  u16* wkt = wqt + NHEAD * ESPL * ESPL;
  u16* wvt = wkt + NHEAD * ESPL * ESPL;
  u16* wt2 = wvt + NHEAD * ESPL * ESPL;          // 2 MB Wf^T bf16
  u16* wt1 = (u16*)(ws + 32 * MB);               // 2 MB W_in^T bf16 (overlaps qb; dead
                                                 // before qkv_mfma writes qb)

  wtrans<<<dim3(16, 16, 1), 256, 0, stream>>>(W_in, wt1, DIMN, DIMN, 0);
  wtrans<<<dim3(16, 16, 1), 256, 0, stream>>>(Wf, wt2, DIMN, DIMN, 0);
  wtrans<<<dim3(2, 2, 8), 256, 0, stream>>>(Wq, wqt, ESPL, ESPL, ESPL * ESPL);
  wtrans<<<dim3(2, 2, 8), 256, 0, stream>>>(Wk, wkt, ESPL, ESPL, ESPL * ESPL);
  wtrans<<<dim3(2, 2, 8), 256, 0, stream>>>(Wv, wvt, ESPL, ESPL, ESPL * ESPL);

  dim3 gg(DIMN / 128, NROWS / 128);  // (8, 64)
  gemm_mfma<0><<<gg, 256, 0, stream>>>(x, wt1, nullptr, nullptr, nullptr, nullptr, nullptr,
                                       nullptr, mod);
  row_stats<<<NROWS, 256, 0, stream>>>(mod, mean1, rstd1);
  qkv_mfma<<<dim3(SEQ / 128, NB * NHEAD), 256, 0, stream>>>(mod, wqt, wkt, wvt, gamma, beta,
                                                            mean1, rstd1, qb, kb, vtb);
  attn_mfma<<<dim3(SEQ / 64, NB * NHEAD), 256, 0, stream>>>(qb, kb, vtb, mod);
  row_stats<<<NROWS, 256, 0, stream>>>(mod, mean2, rstd2);
  gemm_mfma<1><<<gg, 256, 0, stream>>>(mod, wt2, mod, bf, gamma, beta, mean2, rstd2, out);
}

// Round 4
// 394.624 us; speedup vs baseline: 8.3055x; 1.0322x over previous
//
#include <hip/hip_runtime.h>
#include <hip/hip_bf16.h>

#define DIMN 1024
#define NHEAD 8
#define ESPL 128
#define NB 4
#define SEQ 2048
#define NROWS (NB * SEQ)
#define LNEPS 1e-6f

typedef unsigned short u16;
typedef unsigned int u32;
typedef __attribute__((ext_vector_type(8))) short short8;
typedef __attribute__((ext_vector_type(4))) float f32x4;

__device__ __forceinline__ u16 f2bf(float f) {
  u32 u = __float_as_uint(f);
  u += 0x7FFFu + ((u >> 16) & 1u);  // round-to-nearest-even
  return (u16)(u >> 16);
}

__device__ __forceinline__ uint2 pack4bf(float4 v) {
  uint2 r;
  r.x = (u32)f2bf(v.x) | ((u32)f2bf(v.y) << 16);
  r.y = (u32)f2bf(v.z) | ((u32)f2bf(v.w) << 16);
  return r;
}

__device__ __forceinline__ u32 pk2bf(float a, float b) {
  union {
    __hip_bfloat162 h;
    u32 u;
  } cv;
  cv.h = __float22bfloat162_rn(make_float2(a, b));
  return cv.u;
}

__device__ __forceinline__ float eluf(float x) { return x > 0.f ? x : expm1f(x); }

__device__ __forceinline__ float redmax16(float v) {
  v = fmaxf(v, __shfl_xor(v, 1));
  v = fmaxf(v, __shfl_xor(v, 2));
  v = fmaxf(v, __shfl_xor(v, 4));
  v = fmaxf(v, __shfl_xor(v, 8));
  return v;
}
__device__ __forceinline__ float redsum16(float v) {
  v += __shfl_xor(v, 1);
  v += __shfl_xor(v, 2);
  v += __shfl_xor(v, 4);
  v += __shfl_xor(v, 8);
  return v;
}

// ------- weight transpose + fp32->bf16: dst[n*K+k] = bf16(src[k*N+n]) -------
__device__ __forceinline__ void wtrans_body(const float* __restrict__ src,
                                            u16* __restrict__ dst, int K, int N, int n0,
                                            int k0) {
  __shared__ u16 tl[64][68];
  const int t = threadIdx.x;
  const int r = t >> 2;
#pragma unroll
  for (int j = 0; j < 4; j++) {
    int f = (t & 3) + j * 4;
    float4 v = *(const float4*)(src + (size_t)(k0 + r) * N + n0 + f * 4);
    *(uint2*)&tl[r][f * 4] = pack4bf(v);
  }
  __syncthreads();
#pragma unroll
  for (int j = 0; j < 4; j++) {
    int f = (t & 3) + j * 4;
    ushort4 o;
    o.x = tl[f * 4 + 0][r];
    o.y = tl[f * 4 + 1][r];
    o.z = tl[f * 4 + 2][r];
    o.w = tl[f * 4 + 3][r];
    *(ushort4*)(dst + (size_t)(n0 + r) * K + k0 + f * 4) = o;
  }
}

// big: z=0 -> W_in->wt1, z=1 -> Wf->wt2 (1024x1024)
__global__ __launch_bounds__(256) void wtrans_big(const float* __restrict__ sA,
                                                  u16* __restrict__ dA,
                                                  const float* __restrict__ sB,
                                                  u16* __restrict__ dB) {
  const float* s = blockIdx.z ? sB : sA;
  u16* d = blockIdx.z ? dB : dA;
  wtrans_body(s, d, DIMN, DIMN, blockIdx.x * 64, blockIdx.y * 64);
}

// small: z 0..23: mat = z>>3 (Wq/Wk/Wv), head = z&7 (128x128 each)
__global__ __launch_bounds__(256) void wtrans_small(
    const float* __restrict__ sq, const float* __restrict__ sk, const float* __restrict__ sv,
    u16* __restrict__ dq, u16* __restrict__ dk, u16* __restrict__ dv) {
  const int mi = blockIdx.z >> 3, hh = blockIdx.z & 7;
  const float* s = (mi == 0) ? sq : (mi == 1) ? sk : sv;
  u16* d = (mi == 0) ? dq : (mi == 1) ? dk : dv;
  s += (size_t)hh * ESPL * ESPL;
  d += (size_t)hh * ESPL * ESPL;
  wtrans_body(s, d, ESPL, ESPL, blockIdx.x * 64, blockIdx.y * 64);
}

// ------- bf16 MFMA GEMM, 128x128 tile, BK=64, K=1024 -------
// MODE 0: C = A @ Bt^T (A fp32->bf16); also atomicAdd per-row sum/sumsq of C
// MODE 1: C = resid + elu(LN(A) @ Bt^T + bias), LN stats from s1/s2 sums
#define GP 72

template <int MODE>
__global__ __launch_bounds__(256) void gemm_mfma(
    const float* __restrict__ A, const u16* __restrict__ Bt, const float* __restrict__ resid,
    const float* __restrict__ bias, const float* __restrict__ gamma,
    const float* __restrict__ beta, float* __restrict__ s1p, float* __restrict__ s2p,
    float* __restrict__ C) {
  __shared__ u16 Asl[128 * GP];
  __shared__ u16 Bsl[128 * GP];
  const int t = threadIdx.x;
  const int w = t >> 6, lane = t & 63, quad = lane >> 4, l16 = lane & 15;
  const int wm = w & 1, wn = w >> 1;
  const int m0 = blockIdx.y * 128, n0 = blockIdx.x * 128;
  const int sr8 = t >> 3, sf8 = t & 7;
  float mu[4], rsd[4];
  if (MODE == 1) {
#pragma unroll
    for (int p = 0; p < 4; p++) {
      int row = m0 + sr8 + 32 * p;
      float s1 = s1p[row], s2 = s2p[row];
      mu[p] = s1 * (1.f / DIMN);
      rsd[p] = rsqrtf(fmaxf(s2 * (1.f / DIMN) - mu[p] * mu[p], 0.f) + LNEPS);
    }
  }
  f32x4 acc[4][4];
#pragma unroll
  for (int mt = 0; mt < 4; mt++)
#pragma unroll
    for (int nt = 0; nt < 4; nt++) acc[mt][nt] = (f32x4){0.f, 0.f, 0.f, 0.f};

  for (int kt = 0; kt < DIMN; kt += 64) {
    __syncthreads();
#pragma unroll
    for (int p = 0; p < 4; p++) {
      int r = sr8 + 32 * p;
      const float* ap = A + (size_t)(m0 + r) * DIMN + kt;
#pragma unroll
      for (int j = 0; j < 2; j++) {
        int f = sf8 + j * 8;
        float4 v = *(const float4*)(ap + f * 4);
        if (MODE == 1) {
          float4 g = *(const float4*)(gamma + kt + f * 4);
          float4 bb = *(const float4*)(beta + kt + f * 4);
          v.x = (v.x - mu[p]) * rsd[p] * g.x + bb.x;
          v.y = (v.y - mu[p]) * rsd[p] * g.y + bb.y;
          v.z = (v.z - mu[p]) * rsd[p] * g.z + bb.z;
          v.w = (v.w - mu[p]) * rsd[p] * g.w + bb.w;
        }
        *(uint2*)(Asl + r * GP + f * 4) = pack4bf(v);
      }
    }
#pragma unroll
    for (int p = 0; p < 4; p++) {
      int r = sr8 + 32 * p;
      *(uint4*)(Bsl + r * GP + sf8 * 8) = *(const uint4*)(Bt + (size_t)(n0 + r) * DIMN + kt + sf8 * 8);
    }
    __syncthreads();
#pragma unroll
    for (int ks = 0; ks < 64; ks += 32) {
      short8 af[4], bfr[4];
#pragma unroll
      for (int mt = 0; mt < 4; mt++)
        af[mt] = *(const short8*)(Asl + (wm * 64 + mt * 16 + l16) * GP + ks + quad * 8);
#pragma unroll
      for (int nt = 0; nt < 4; nt++)
        bfr[nt] = *(const short8*)(Bsl + (wn * 64 + nt * 16 + l16) * GP + ks + quad * 8);
#pragma unroll
      for (int mt = 0; mt < 4; mt++)
#pragma unroll
        for (int nt = 0; nt < 4; nt++)
          acc[mt][nt] = __builtin_amdgcn_mfma_f32_16x16x32_bf16(af[mt], bfr[nt], acc[mt][nt], 0, 0, 0);
    }
  }
  // epilogue
#pragma unroll
  for (int mt = 0; mt < 4; mt++) {
#pragma unroll
    for (int r = 0; r < 4; r++) {
      int row = m0 + wm * 64 + mt * 16 + quad * 4 + r;
      float s1 = 0.f, s2 = 0.f;
#pragma unroll
      for (int nt = 0; nt < 4; nt++) {
        int col = n0 + wn * 64 + nt * 16 + l16;
        size_t off = (size_t)row * DIMN + col;
        float v = acc[mt][nt][r];
        if (MODE == 0) {
          C[off] = v;
          s1 += v;
          s2 += v * v;
        } else {
          C[off] = resid[off] + eluf(v + bias[col]);
        }
      }
      if (MODE == 0) {
        s1 = redsum16(s1);
        s2 = redsum16(s2);
        if (l16 == 0) {
          atomicAdd(s1p + row, s1);
          atomicAdd(s2p + row, s2);
        }
      }
    }
  }
}

// ------- QKV: per (b,h), 128 s-rows x 128 e, K=128; LN1 fused in A-staging -------
#define QP 136

__global__ __launch_bounds__(256) void qkv_mfma(
    const float* __restrict__ modp, const u16* __restrict__ wqt, const u16* __restrict__ wkt,
    const u16* __restrict__ wvt, const float* __restrict__ gamma, const float* __restrict__ beta,
    const float* __restrict__ s1p, const float* __restrict__ s2p, u16* __restrict__ qo,
    u16* __restrict__ ko, u16* __restrict__ vto) {
  __shared__ u16 Asl[128 * QP];
  __shared__ u16 Bsl[128 * QP];
  const int t = threadIdx.x;
  const int w = t >> 6, lane = t & 63, quad = lane >> 4, l16 = lane & 15;
  const int wm = w & 1, wn = w >> 1;
  const int s0 = blockIdx.x * 128;
  const int bh = blockIdx.y;
  const int b = bh >> 3, hh = bh & 7;
  const int sr8 = t >> 3, sf8 = t & 7;
#pragma unroll
  for (int p = 0; p < 4; p++) {
    int r = sr8 + 32 * p;
    int rowg = b * SEQ + s0 + r;
    float s1 = s1p[rowg], s2 = s2p[rowg];
    float mu = s1 * (1.f / DIMN);
    float rsd = rsqrtf(fmaxf(s2 * (1.f / DIMN) - mu * mu, 0.f) + LNEPS);
    const float* ap = modp + (size_t)rowg * DIMN + hh * ESPL;
#pragma unroll
    for (int j = 0; j < 4; j++) {
      int f = sf8 + j * 8;
      float4 v = *(const float4*)(ap + f * 4);
      float4 g = *(const float4*)(gamma + hh * ESPL + f * 4);
      float4 bb = *(const float4*)(beta + hh * ESPL + f * 4);
      v.x = (v.x - mu) * rsd * g.x + bb.x;
      v.y = (v.y - mu) * rsd * g.y + bb.y;
      v.z = (v.z - mu) * rsd * g.z + bb.z;
      v.w = (v.w - mu) * rsd * g.w + bb.w;
      *(uint2*)(Asl + r * QP + f * 4) = pack4bf(v);
    }
  }
  __syncthreads();
  short8 afr[4][4];
#pragma unroll
  for (int k4 = 0; k4 < 4; k4++)
#pragma unroll
    for (int mt = 0; mt < 4; mt++)
      afr[k4][mt] = *(const short8*)(Asl + (wm * 64 + mt * 16 + l16) * QP + k4 * 32 + quad * 8);

  const u16* Ws[3] = {wqt, wkt, wvt};
  for (int mi = 0; mi < 3; mi++) {
    __syncthreads();
    const u16* wsrc = Ws[mi] + ((size_t)hh << 14);
#pragma unroll
    for (int p = 0; p < 4; p++) {
      int r = sr8 + 32 * p;
#pragma unroll
      for (int j = 0; j < 2; j++) {
        int f = sf8 + j * 8;
        *(uint4*)(Bsl + r * QP + f * 8) = *(const uint4*)(wsrc + r * ESPL + f * 8);
      }
    }
    __syncthreads();
    f32x4 acc[4][4];
#pragma unroll
    for (int mt = 0; mt < 4; mt++)
#pragma unroll
      for (int nt = 0; nt < 4; nt++) acc[mt][nt] = (f32x4){0.f, 0.f, 0.f, 0.f};
#pragma unroll
    for (int k4 = 0; k4 < 4; k4++) {
      short8 bfr[4];
#pragma unroll
      for (int nt = 0; nt < 4; nt++)
        bfr[nt] = *(const short8*)(Bsl + (wn * 64 + nt * 16 + l16) * QP + k4 * 32 + quad * 8);
#pragma unroll
      for (int mt = 0; mt < 4; mt++)
#pragma unroll
        for (int nt = 0; nt < 4; nt++)
          acc[mt][nt] = __builtin_amdgcn_mfma_f32_16x16x32_bf16(afr[k4][mt], bfr[nt], acc[mt][nt], 0, 0, 0);
    }
    if (mi < 2) {
      u16* o = (mi == 0) ? qo : ko;
#pragma unroll
      for (int mt = 0; mt < 4; mt++)
#pragma unroll
        for (int r = 0; r < 4; r++) {
          int s = s0 + wm * 64 + mt * 16 + quad * 4 + r;
#pragma unroll
          for (int nt = 0; nt < 4; nt++) {
            int e = wn * 64 + nt * 16 + l16;
            o[((size_t)bh * SEQ + s) * ESPL + e] = f2bf(acc[mt][nt][r]);
          }
        }
    } else {
#pragma unroll
      for (int mt = 0; mt < 4; mt++)
#pragma unroll
        for (int nt = 0; nt < 4; nt++) {
          int e = wn * 64 + nt * 16 + l16;
          int sbase = s0 + wm * 64 + mt * 16 + quad * 4;
          ushort4 pk;
          pk.x = f2bf(acc[mt][nt][0]);
          pk.y = f2bf(acc[mt][nt][1]);
          pk.z = f2bf(acc[mt][nt][2]);
          pk.w = f2bf(acc[mt][nt][3]);
          *(ushort4*)(vto + ((size_t)bh * ESPL + e) * SEQ + sbase) = pk;
        }
    }
  }
}

// ------- MFMA flash attention v2: 128-row q-tile, 2 m-tiles/wave, reg softmax -------
// q,k: [b,h,s,e] bf16; vt: [b,h,e,s] bf16. mod += softmax(QK^T)V; row sums atomics.
#define KP 136   // Ks pitch (u16): 64 kv-rows x 128 e
#define VP 72    // Vs pitch (u16): 128 e-rows x 64 s
#define PTP 36   // Pt pitch (u16): per-wave P^T, 64 cols x 32 rows-local

__global__ __launch_bounds__(256, 2) void attn_mfma(const u16* __restrict__ q,
                                                    const u16* __restrict__ kk,
                                                    const u16* __restrict__ vt,
                                                    float* __restrict__ modp,
                                                    float* __restrict__ s1p,
                                                    float* __restrict__ s2p) {
  __shared__ u16 Ks[64 * KP];      // 17408 B
  __shared__ u16 Vs[128 * VP];     // 18432 B
  __shared__ u16 Pt[4][64 * PTP];  // 4 x 4608 B (wave-private P^T)
  const int t = threadIdx.x;
  const int w = t >> 6, lane = t & 63, quad = lane >> 4, l16 = lane & 15;
  const int qt = blockIdx.x;  // 0..15
  const int bh = blockIdx.y;  // 0..31
  const size_t qkbase = (size_t)bh * SEQ * ESPL;
  const int qrow0 = qt * 128 + w * 32;  // wave's first q-row
  u16* Ptw = Pt[w];

  // Q A-frags: 2 m-tiles x 4 k-chunks, held in registers for all iterations
  short8 qf[2][4];
#pragma unroll
  for (int mt = 0; mt < 2; mt++) {
    const u16* qrow = q + qkbase + (size_t)(qrow0 + mt * 16 + l16) * ESPL + quad * 8;
#pragma unroll
    for (int kc = 0; kc < 4; kc++) qf[mt][kc] = *(const short8*)(qrow + kc * 32);
  }

  float m_st[2][4], l_st[2][4];
#pragma unroll
  for (int mt = 0; mt < 2; mt++)
#pragma unroll
    for (int r = 0; r < 4; r++) {
      m_st[mt][r] = -1e30f;
      l_st[mt][r] = 0.f;
    }
  f32x4 oacc[2][8];
#pragma unroll
  for (int mt = 0; mt < 2; mt++)
#pragma unroll
    for (int n = 0; n < 8; n++) oacc[mt][n] = (f32x4){0.f, 0.f, 0.f, 0.f};

  for (int kt = 0; kt < SEQ / 64; kt++) {
    __syncthreads();  // all waves done reading Ks/Vs
    {
      const u16* kg = kk + qkbase + (size_t)kt * 64 * ESPL;
      const u16* vg = vt + qkbase + (size_t)kt * 64;
#pragma unroll
      for (int i = 0; i < 4; i++) {
        int p = t + (i << 8);
        int r = p >> 4, c = (p & 15) << 3;
        *(uint4*)(Ks + r * KP + c) = *(const uint4*)(kg + r * ESPL + c);
      }
#pragma unroll
      for (int i = 0; i < 4; i++) {
        int p = t + (i << 8);
        int e = p >> 3, c = (p & 7) << 3;
        *(uint4*)(Vs + e * VP + c) = *(const uint4*)(vg + (size_t)e * SEQ + c);
      }
    }
    __syncthreads();
    // QK^T: 2 m-tiles x 4 c-tiles; K-frags shared across m-tiles
    f32x4 sacc[2][4];
#pragma unroll
    for (int mt = 0; mt < 2; mt++)
#pragma unroll
      for (int c = 0; c < 4; c++) sacc[mt][c] = (f32x4){0.f, 0.f, 0.f, 0.f};
#pragma unroll
    for (int c = 0; c < 4; c++) {
#pragma unroll
      for (int kc = 0; kc < 4; kc++) {
        short8 kf = *(const short8*)(Ks + (c * 16 + l16) * KP + kc * 32 + quad * 8);
        sacc[0][c] = __builtin_amdgcn_mfma_f32_16x16x32_bf16(qf[0][kc], kf, sacc[0][c], 0, 0, 0);
        sacc[1][c] = __builtin_amdgcn_mfma_f32_16x16x32_bf16(qf[1][kc], kf, sacc[1][c], 0, 0, 0);
      }
    }
    // register online softmax; write P^T bf16 to wave-private LDS
    float alpha[2][4];
#pragma unroll
    for (int mt = 0; mt < 2; mt++) {
      float mx[4], sum[4];
#pragma unroll
      for (int r = 0; r < 4; r++) {
        float m4 = fmaxf(fmaxf(sacc[mt][0][r], sacc[mt][1][r]),
                         fmaxf(sacc[mt][2][r], sacc[mt][3][r]));
        mx[r] = fmaxf(m_st[mt][r], redmax16(m4));
        alpha[mt][r] = __expf(m_st[mt][r] - mx[r]);
        m_st[mt][r] = mx[r];
        sum[r] = 0.f;
      }
#pragma unroll
      for (int c = 0; c < 4; c++) {
        float p0 = __expf(sacc[mt][c][0] - mx[0]);
        float p1 = __expf(sacc[mt][c][1] - mx[1]);
        float p2 = __expf(sacc[mt][c][2] - mx[2]);
        float p3 = __expf(sacc[mt][c][3] - mx[3]);
        sum[0] += p0;
        sum[1] += p1;
        sum[2] += p2;
        sum[3] += p3;
        // P^T[col][rowlocal]: col = c*16+l16, rowlocal = mt*16 + quad*4 + r
        *(uint2*)(Ptw + (size_t)(c * 16 + l16) * PTP + mt * 16 + quad * 4) =
            make_uint2(pk2bf(p0, p1), pk2bf(p2, p3));
      }
#pragma unroll
      for (int r = 0; r < 4; r++) {
        l_st[mt][r] = l_st[mt][r] * alpha[mt][r] + redsum16(sum[r]);
      }
    }
    // rescale O
#pragma unroll
    for (int mt = 0; mt < 2; mt++)
#pragma unroll
      for (int n = 0; n < 8; n++)
#pragma unroll
        for (int r = 0; r < 4; r++) oacc[mt][n][r] *= alpha[mt][r];
    // P A-frags (wave-private, no barrier): gather from P^T
    short8 pa[2][2];
#pragma unroll
    for (int mt = 0; mt < 2; mt++)
#pragma unroll
      for (int kb = 0; kb < 2; kb++) {
        const u16* pcol = Ptw + (size_t)(kb * 32 + quad * 8) * PTP + mt * 16 + l16;
        short8 v;
#pragma unroll
        for (int j = 0; j < 8; j++) v[j] = (short)pcol[j * PTP];
        pa[mt][kb] = v;
      }
    // P @ V: V-frags shared across m-tiles
#pragma unroll
    for (int n = 0; n < 8; n++) {
      short8 v0 = *(const short8*)(Vs + (n * 16 + l16) * VP + quad * 8);
      short8 v1 = *(const short8*)(Vs + (n * 16 + l16) * VP + 32 + quad * 8);
      oacc[0][n] = __builtin_amdgcn_mfma_f32_16x16x32_bf16(pa[0][0], v0, oacc[0][n], 0, 0, 0);
      oacc[0][n] = __builtin_amdgcn_mfma_f32_16x16x32_bf16(pa[0][1], v1, oacc[0][n], 0, 0, 0);
      oacc[1][n] = __builtin_amdgcn_mfma_f32_16x16x32_bf16(pa[1][0], v0, oacc[1][n], 0, 0, 0);
      oacc[1][n] = __builtin_amdgcn_mfma_f32_16x16x32_bf16(pa[1][1], v1, oacc[1][n], 0, 0, 0);
    }
  }
  // epilogue: normalize, RMW into mod, per-row sum/sumsq atomics
  const int b = bh >> 3, hh = bh & 7;
#pragma unroll
  for (int mt = 0; mt < 2; mt++) {
#pragma unroll
    for (int r = 0; r < 4; r++) {
      int row = qrow0 + mt * 16 + quad * 4 + r;
      float linv = 1.f / l_st[mt][r];
      float* mp = modp + ((size_t)(b * SEQ + row)) * DIMN + hh * ESPL + l16;
      float s1 = 0.f, s2 = 0.f;
#pragma unroll
      for (int n = 0; n < 8; n++) {
        float vnew = mp[n * 16] + oacc[mt][n][r] * linv;
        mp[n * 16] = vnew;
        s1 += vnew;
        s2 += vnew * vnew;
      }
      s1 = redsum16(s1);
      s2 = redsum16(s2);
      if (l16 == 0) {
        atomicAdd(s1p + b * SEQ + row, s1);
        atomicAdd(s2p + b * SEQ + row, s2);
      }
    }
  }
}

extern "C" void kernel_launch(void* const* d_in, const int* in_sizes, int n_in, void* d_out,
                              int out_size, void* d_ws, size_t ws_size, hipStream_t stream) {
  (void)in_sizes;
  (void)n_in;
  (void)out_size;
  (void)ws_size;
  const float* x = (const float*)d_in[0];
  const float* W_in = (const float*)d_in[1];
  const float* gamma = (const float*)d_in[2];
  const float* beta = (const float*)d_in[3];
  const float* Wq = (const float*)d_in[4];
  const float* Wk = (const float*)d_in[5];
  const float* Wv = (const float*)d_in[6];
  const float* Wf = (const float*)d_in[7];
  const float* bf = (const float*)d_in[8];
  float* out = (float*)d_out;

  char* ws = (char*)d_ws;
  const size_t MB = 1024ull * 1024;
  float* mod = (float*)ws;                 // 32 MB fp32 [8192,1024]
  u16* qb = (u16*)(ws + 32 * MB);          // 16 MB bf16 [B,H,S,E]
  u16* kb = (u16*)(ws + 48 * MB);          // 16 MB bf16 [B,H,S,E]
  u16* vtb = (u16*)(ws + 64 * MB);         // 16 MB bf16 [B,H,E,S]
  float* sums = (float*)(ws + 80 * MB);    // 4 x 32 KB: s1a,s2a,s1b,s2b
  float* s1a = sums;
  float* s2a = s1a + NROWS;
  float* s1b = s2a + NROWS;
  float* s2b = s1b + NROWS;
  u16* wqt = (u16*)(ws + 80 * MB + 4 * NROWS * sizeof(float));
  u16* wkt = wqt + NHEAD * ESPL * ESPL;
  u16* wvt = wkt + NHEAD * ESPL * ESPL;
  u16* wt2 = wvt + NHEAD * ESPL * ESPL;  // 2 MB Wf^T bf16
  u16* wt1 = (u16*)(ws + 32 * MB);       // W_in^T bf16 overlaps qb (dead before qkv writes qb)

  hipMemsetAsync(sums, 0, 4 * NROWS * sizeof(float), stream);
  wtrans_big<<<dim3(16, 16, 2), 256, 0, stream>>>(W_in, wt1, Wf, wt2);
  wtrans_small<<<dim3(2, 2, 24), 256, 0, stream>>>(Wq, Wk, Wv, wqt, wkt, wvt);

  dim3 gg(DIMN / 128, NROWS / 128);  // (8, 64)
  gemm_mfma<0><<<gg, 256, 0, stream>>>(x, wt1, nullptr, nullptr, nullptr, nullptr, s1a, s2a, mod);
  qkv_mfma<<<dim3(SEQ / 128, NB * NHEAD), 256, 0, stream>>>(mod, wqt, wkt, wvt, gamma, beta,
                                                            s1a, s2a, qb, kb, vtb);
  attn_mfma<<<dim3(SEQ / 128, NB * NHEAD), 256, 0, stream>>>(qb, kb, vtb, mod, s1b, s2b);
  gemm_mfma<1><<<gg, 256, 0, stream>>>(mod, wt2, mod, bf, gamma, beta, s1b, s2b, out);
}